// Round 2
// baseline (937.817 us; speedup 1.0000x reference)
//
#include <hip/hip_runtime.h>
#include <hip/hip_bf16.h>
#include <float.h>

// SplitNN: out1 = x1@W1+b1; sens = max-min of row-L1(out1); out1 += noise*sens*7.5;
// out1 *= rr_mask; out2 = x2@W2+b2; out = min(out1,out2)@Ws + bs
// B=262144, F=160, H=128, C=10, fp32 in/out.
//
// v2: transposed MFMA (D[h][batch]) so per-lane regs are contiguous in h ->
// float4 noise loads, float4 bias acc-init, MFMA head via tiny LDS transpose.
// No mm1 materialization (k2 recomputes out1). Weights pre-transposed to bf16
// in ws by k0, fragments loaded from global (L1/L2-hot). LDS ~17KB -> 3 blk/CU.

typedef __bf16 bf16x8 __attribute__((ext_vector_type(8)));
typedef __bf16 bf16x4 __attribute__((ext_vector_type(4)));
typedef float  f32x4  __attribute__((ext_vector_type(4)));

#define FDIM 160
#define HDIM 128
#define SROW 136   // sbuf row stride (bf16): 16B-aligned, breaks power-of-2 banks

__global__ void k0_prep(const float* __restrict__ W1, const float* __restrict__ W2,
                        unsigned int* __restrict__ mmx,
                        __bf16* __restrict__ w1t, __bf16* __restrict__ w2t) {
    int tid = blockIdx.x * 256 + threadIdx.x;
    if (tid == 0) { mmx[0] = 0x7F7FFFFFu; /* FLT_MAX */ mmx[1] = 0u; }
    for (int idx = tid; idx < FDIM * HDIM; idx += gridDim.x * 256) {
        int k = idx >> 7, n = idx & 127;      // W[k][n] row-major
        w1t[n * FDIM + k] = (__bf16)W1[idx];
        w2t[n * FDIM + k] = (__bf16)W2[idx];
    }
}

__device__ __forceinline__ bf16x8 cvt8(const float* __restrict__ p) {
    f32x4 f0 = *(const f32x4*)p;
    f32x4 f1 = *(const f32x4*)(p + 4);
    bf16x8 a;
    a[0] = (__bf16)f0[0]; a[1] = (__bf16)f0[1]; a[2] = (__bf16)f0[2]; a[3] = (__bf16)f0[3];
    a[4] = (__bf16)f1[0]; a[5] = (__bf16)f1[1]; a[6] = (__bf16)f1[2]; a[7] = (__bf16)f1[3];
    return a;
}

// K1: row-L1 norms of x1@W1+b1 -> global min/max atomics. No stores of out1.
__global__ __launch_bounds__(256, 4) void k1_sens(
    const float* __restrict__ x1, const float* __restrict__ b1,
    const __bf16* __restrict__ w1t, unsigned int* __restrict__ mmx, int B)
{
    __shared__ float smin[4], smax[4];
    const int lane = threadIdx.x & 63;
    const int wv   = threadIdx.x >> 6;
    const int m    = lane & 15;   // batch col (B-operand row)
    const int q    = lane >> 4;

    float wmin = FLT_MAX, wmax = 0.0f;
    const int nslab = B >> 4;
    for (int slab = blockIdx.x * 4 + wv; slab < nslab; slab += gridDim.x * 4) {
        const int r0 = slab << 4;
        f32x4 acc[8];
        #pragma unroll
        for (int ct = 0; ct < 8; ++ct) acc[ct] = *(const f32x4*)&b1[ct * 16 + q * 4];
        const float* xrow = x1 + (size_t)(r0 + m) * FDIM + q * 8;
        #pragma unroll
        for (int ks = 0; ks < 5; ++ks) {
            bf16x8 xf = cvt8(xrow + ks * 32);
            #pragma unroll
            for (int ct = 0; ct < 8; ++ct) {
                bf16x8 wf = *(const bf16x8*)(w1t + (ct * 16 + m) * FDIM + ks * 32 + q * 8);
                acc[ct] = __builtin_amdgcn_mfma_f32_16x16x32_bf16(wf, xf, acc[ct], 0, 0, 0);
            }
        }
        // lane (m,q) holds out1[h=16ct+4q+reg][batch=r0+m]
        float ns = 0.0f;
        #pragma unroll
        for (int ct = 0; ct < 8; ++ct)
            #pragma unroll
            for (int reg = 0; reg < 4; ++reg) ns += fabsf(acc[ct][reg]);
        ns += __shfl_xor(ns, 16, 64);   // sum over quads -> full L1 norm of row r0+m
        ns += __shfl_xor(ns, 32, 64);
        float mn = ns, mx = ns;
        #pragma unroll
        for (int off = 1; off < 16; off <<= 1) {
            mn = fminf(mn, __shfl_xor(mn, off, 64));
            mx = fmaxf(mx, __shfl_xor(mx, off, 64));
        }
        wmin = fminf(wmin, mn);
        wmax = fmaxf(wmax, mx);
    }
    if (lane == 0) { smin[wv] = wmin; smax[wv] = wmax; }
    __syncthreads();
    if (threadIdx.x == 0) {
        float bmin = fminf(fminf(smin[0], smin[1]), fminf(smin[2], smin[3]));
        float bmax = fmaxf(fmaxf(smax[0], smax[1]), fmaxf(smax[2], smax[3]));
        atomicMin(&mmx[0], __float_as_uint(bmin));  // norms >= 0: uint order == float order
        atomicMax(&mmx[1], __float_as_uint(bmax));
    }
}

// K2: recompute out1, compute out2, combine, MFMA head, store out.
__global__ __launch_bounds__(256, 3) void k2_main(
    const float* __restrict__ x1, const float* __restrict__ x2,
    const float* __restrict__ b1, const float* __restrict__ b2,
    const float* __restrict__ Ws, const float* __restrict__ bs,
    const float* __restrict__ noise, const float* __restrict__ rru,
    const __bf16* __restrict__ w1t, const __bf16* __restrict__ w2t,
    const unsigned int* __restrict__ mmx, float* __restrict__ out, int B)
{
    __shared__ __align__(16) __bf16 sbuf[4][16 * SROW];  // per-wave s-transpose tile

    const int lane = threadIdx.x & 63;
    const int wv   = threadIdx.x >> 6;
    const int m    = lane & 15;
    const int q    = lane >> 4;

    const float noise_mul = (__uint_as_float(mmx[1]) - __uint_as_float(mmx[0])) * 7.5f;

    // rr mask as 32-bit register: bit(ct*4+reg) = keep h=16ct+4q+reg
    unsigned rmask = 0;
    #pragma unroll
    for (int ct = 0; ct < 8; ++ct) {
        f32x4 r4 = *(const f32x4*)&rru[ct * 16 + q * 4];
        #pragma unroll
        for (int reg = 0; reg < 4; ++reg)
            if (r4[reg] < 0.95f) rmask |= 1u << (ct * 4 + reg);
    }
    // Ws B-fragments (c = lane&15, k = q*8+j), pad c>=10 with 0
    bf16x8 wsf[4];
    #pragma unroll
    for (int ks2 = 0; ks2 < 4; ++ks2)
        #pragma unroll
        for (int j = 0; j < 8; ++j) {
            int h = ks2 * 32 + q * 8 + j;
            wsf[ks2][j] = (__bf16)((m < 10) ? Ws[h * 10 + m] : 0.0f);
        }
    const float bsv = (m < 10) ? bs[m] : 0.0f;

    const int nslab = B >> 4;
    for (int slab = blockIdx.x * 4 + wv; slab < nslab; slab += gridDim.x * 4) {
        const int r0 = slab << 4;
        f32x4 acc1[8], acc2[8];
        #pragma unroll
        for (int ct = 0; ct < 8; ++ct) {
            acc1[ct] = *(const f32x4*)&b1[ct * 16 + q * 4];
            acc2[ct] = *(const f32x4*)&b2[ct * 16 + q * 4];
        }
        const float* x1row = x1 + (size_t)(r0 + m) * FDIM + q * 8;
        const float* x2row = x2 + (size_t)(r0 + m) * FDIM + q * 8;
        #pragma unroll
        for (int ks = 0; ks < 5; ++ks) {
            bf16x8 a1 = cvt8(x1row + ks * 32);
            bf16x8 a2 = cvt8(x2row + ks * 32);
            #pragma unroll
            for (int ct = 0; ct < 8; ++ct) {
                bf16x8 w1f = *(const bf16x8*)(w1t + (ct * 16 + m) * FDIM + ks * 32 + q * 8);
                acc1[ct] = __builtin_amdgcn_mfma_f32_16x16x32_bf16(w1f, a1, acc1[ct], 0, 0, 0);
                bf16x8 w2f = *(const bf16x8*)(w2t + (ct * 16 + m) * FDIM + ks * 32 + q * 8);
                acc2[ct] = __builtin_amdgcn_mfma_f32_16x16x32_bf16(w2f, a2, acc2[ct], 0, 0, 0);
            }
        }
        // combine: s[h][batch=m], lane's 4 regs contiguous in h -> float4 noise
        #pragma unroll
        for (int ct = 0; ct < 8; ++ct) {
            f32x4 nz = *(const f32x4*)&noise[(size_t)(r0 + m) * HDIM + ct * 16 + q * 4];
            bf16x4 pk;
            #pragma unroll
            for (int reg = 0; reg < 4; ++reg) {
                float v1 = acc1[ct][reg] + nz[reg] * noise_mul;
                v1 = ((rmask >> (ct * 4 + reg)) & 1u) ? v1 : 0.0f;
                pk[reg] = (__bf16)fminf(v1, acc2[ct][reg]);
            }
            *(bf16x4*)&sbuf[wv][m * SROW + ct * 16 + q * 4] = pk;  // row=batch, col=h
        }
        // head: D[batch][c] = s @ Ws  (A from LDS, B in regs), bias-initialized
        f32x4 d = {bsv, bsv, bsv, bsv};
        #pragma unroll
        for (int ks2 = 0; ks2 < 4; ++ks2) {
            bf16x8 sf = *(const bf16x8*)&sbuf[wv][m * SROW + ks2 * 32 + q * 8];
            d = __builtin_amdgcn_mfma_f32_16x16x32_bf16(sf, wsf[ks2], d, 0, 0, 0);
        }
        if (m < 10) {
            #pragma unroll
            for (int reg = 0; reg < 4; ++reg)
                out[(size_t)(r0 + q * 4 + reg) * 10 + m] = d[reg];
        }
    }
}

extern "C" void kernel_launch(void* const* d_in, const int* in_sizes, int n_in,
                              void* d_out, int out_size, void* d_ws, size_t ws_size,
                              hipStream_t stream) {
    const float* x1    = (const float*)d_in[0];
    const float* x2    = (const float*)d_in[1];
    const float* W1    = (const float*)d_in[2];
    const float* b1    = (const float*)d_in[3];
    const float* W2    = (const float*)d_in[4];
    const float* b2    = (const float*)d_in[5];
    const float* Ws    = (const float*)d_in[6];
    const float* bs    = (const float*)d_in[7];
    const float* noise = (const float*)d_in[8];
    const float* rru   = (const float*)d_in[9];
    float* out = (float*)d_out;
    const int B = in_sizes[0] / FDIM;

    unsigned int* mmx = (unsigned int*)d_ws;
    __bf16* w1t = (__bf16*)((char*)d_ws + 256);                 // 160*128*2 = 40960 B
    __bf16* w2t = (__bf16*)((char*)d_ws + 256 + 40960);

    hipLaunchKernelGGL(k0_prep, dim3(64), dim3(256), 0, stream, W1, W2, mmx, w1t, w2t);
    hipLaunchKernelGGL(k1_sens, dim3(1024), dim3(256), 0, stream, x1, b1, w1t, mmx, B);
    hipLaunchKernelGGL(k2_main, dim3(768), dim3(256), 0, stream,
                       x1, x2, b1, b2, Ws, bs, noise, rru, w1t, w2t, mmx, out, B);
}

// Round 3
// 482.736 us; speedup vs baseline: 1.9427x; 1.9427x over previous
//
#include <hip/hip_runtime.h>
#include <hip/hip_bf16.h>
#include <float.h>

// SplitNN v3: weights in registers (per-wave h-split), x/noise staged via
// global_load_lds (async, double-buffered), dense dwordx4 out stores.
// B=262144, F=160, H=128, C=10, fp32 in/out.

typedef __bf16 bf16x8 __attribute__((ext_vector_type(8)));
typedef __bf16 bf16x4 __attribute__((ext_vector_type(4)));
typedef float  f32x4  __attribute__((ext_vector_type(4)));

#define FDIM 160
#define HDIM 128
#define SROW 132   // sbuf bf16 stride: 264B rows -> <=4-way LDS aliasing on head reads

#define GL2LDS(g, l) __builtin_amdgcn_global_load_lds( \
    (const __attribute__((address_space(1))) unsigned int*)(g), \
    (__attribute__((address_space(3))) unsigned int*)(l), 16, 0, 0)

__global__ void k0_prep(const float* __restrict__ W1, const float* __restrict__ W2,
                        unsigned int* __restrict__ mmx,
                        __bf16* __restrict__ w1t, __bf16* __restrict__ w2t) {
    int tid = blockIdx.x * 256 + threadIdx.x;
    if (tid == 0) { mmx[0] = 0x7F7FFFFFu; /* FLT_MAX */ mmx[1] = 0u; }
    for (int idx = tid; idx < FDIM * HDIM; idx += gridDim.x * 256) {
        int k = idx >> 7, n = idx & 127;      // W[k][n] row-major
        w1t[n * FDIM + k] = (__bf16)W1[idx];
        w2t[n * FDIM + k] = (__bf16)W2[idx];
    }
}

__device__ __forceinline__ bf16x8 pack8(f32x4 lo, f32x4 hi) {
    bf16x8 a;
    a[0] = (__bf16)lo[0]; a[1] = (__bf16)lo[1]; a[2] = (__bf16)lo[2]; a[3] = (__bf16)lo[3];
    a[4] = (__bf16)hi[0]; a[5] = (__bf16)hi[1]; a[6] = (__bf16)hi[2]; a[7] = (__bf16)hi[3];
    return a;
}

// K1: global min/max of row-L1(x1@W1+b1). Wave wv owns h-tiles ct in {2wv,2wv+1};
// per-slab cross-wave norm sum via parity-double-buffered LDS.
__global__ __launch_bounds__(256, 4) void k1_sens(
    const float* __restrict__ x1, const float* __restrict__ b1,
    const __bf16* __restrict__ w1t, unsigned int* __restrict__ mmx, int B)
{
    __shared__ __align__(16) char stg[2][10 * 1024];   // x1 slab tile, lane-major chunks
    __shared__ float nbuf[2][4][16];                   // [parity][wave][batch-row]

    const int lane = threadIdx.x & 63;
    const int wv   = threadIdx.x >> 6;
    const int m    = lane & 15;
    const int q    = lane >> 4;

    bf16x8 wf[2][5];
    f32x4  bv[2];
    #pragma unroll
    for (int cc = 0; cc < 2; ++cc) {
        const int ct = 2 * wv + cc;
        bv[cc] = *(const f32x4*)&b1[ct * 16 + q * 4];
        #pragma unroll
        for (int ks = 0; ks < 5; ++ks)
            wf[cc][ks] = *(const bf16x8*)(w1t + (ct * 16 + m) * FDIM + ks * 32 + q * 8);
    }

    const int nslab = B >> 4;
    auto stage = [&](int buf, int slab) {
        const float* rowp = x1 + (size_t)((slab << 4) + m) * FDIM + q * 8;
        for (int c = wv; c < 10; c += 4)                  // c uniform per wave
            GL2LDS(rowp + (c >> 1) * 32 + (c & 1) * 4, &stg[buf][c * 1024]);
    };

    float wmin = FLT_MAX, wmax = 0.0f;
    int it = blockIdx.x, cur = 0, iter = 0;
    stage(0, it);
    for (; it < nslab; it += gridDim.x) {
        asm volatile("s_waitcnt vmcnt(0)" ::: "memory");
        __syncthreads();                                  // buf[cur] staged; nbuf published
        if (iter > 0 && wv == 0 && lane < 16) {
            const int pb = (iter - 1) & 1;
            float nrm = nbuf[pb][0][m] + nbuf[pb][1][m] + nbuf[pb][2][m] + nbuf[pb][3][m];
            wmin = fminf(wmin, nrm); wmax = fmaxf(wmax, nrm);
        }
        if (it + (int)gridDim.x < nslab) stage(cur ^ 1, it + gridDim.x);

        f32x4 acc[2] = { bv[0], bv[1] };
        #pragma unroll
        for (int ks = 0; ks < 5; ++ks) {
            f32x4 lo = *(const f32x4*)&stg[cur][(2 * ks) * 1024 + lane * 16];
            f32x4 hi = *(const f32x4*)&stg[cur][(2 * ks + 1) * 1024 + lane * 16];
            bf16x8 a = pack8(lo, hi);
            acc[0] = __builtin_amdgcn_mfma_f32_16x16x32_bf16(wf[0][ks], a, acc[0], 0, 0, 0);
            acc[1] = __builtin_amdgcn_mfma_f32_16x16x32_bf16(wf[1][ks], a, acc[1], 0, 0, 0);
        }
        float part = 0.0f;
        #pragma unroll
        for (int cc = 0; cc < 2; ++cc)
            #pragma unroll
            for (int reg = 0; reg < 4; ++reg) part += fabsf(acc[cc][reg]);
        part += __shfl_xor(part, 16, 64);
        part += __shfl_xor(part, 32, 64);
        if (lane < 16) nbuf[iter & 1][wv][m] = part;
        cur ^= 1; ++iter;
    }
    __syncthreads();
    if (iter > 0 && wv == 0 && lane < 16) {
        const int pb = (iter - 1) & 1;
        float nrm = nbuf[pb][0][m] + nbuf[pb][1][m] + nbuf[pb][2][m] + nbuf[pb][3][m];
        wmin = fminf(wmin, nrm); wmax = fmaxf(wmax, nrm);
    }
    if (wv == 0) {
        #pragma unroll
        for (int off = 1; off < 16; off <<= 1) {
            wmin = fminf(wmin, __shfl_xor(wmin, off, 64));
            wmax = fmaxf(wmax, __shfl_xor(wmax, off, 64));
        }
        if (lane == 0) {
            atomicMin(&mmx[0], __float_as_uint(wmin));  // norms >= 0: uint order == float order
            atomicMax(&mmx[1], __float_as_uint(wmax));
        }
    }
}

// K2: recompute out1 + out2 (weights in regs), combine with noise/mask/min,
// MFMA head, dense contiguous out stores.
__global__ __launch_bounds__(256, 2) void k2_main(
    const float* __restrict__ x1, const float* __restrict__ x2,
    const float* __restrict__ b1, const float* __restrict__ b2,
    const float* __restrict__ Ws, const float* __restrict__ bs,
    const float* __restrict__ noise, const float* __restrict__ rru,
    const __bf16* __restrict__ w1t, const __bf16* __restrict__ w2t,
    const unsigned int* __restrict__ mmx, float* __restrict__ out, int B)
{
    __shared__ __align__(16) char   stg[2][28 * 1024];  // chunks: 0-9 x1, 10-19 x2, 20-27 noise
    __shared__ __align__(16) __bf16 sbuf[16 * SROW];    // s tile [batch][h]
    __shared__ __align__(16) float  obuf[160];          // out tile [16][10]

    const int lane = threadIdx.x & 63;
    const int wv   = threadIdx.x >> 6;
    const int m    = lane & 15;
    const int q    = lane >> 4;

    const float noise_mul = (__uint_as_float(mmx[1]) - __uint_as_float(mmx[0])) * 7.5f;

    bf16x8 wf1[2][5], wf2[2][5];
    f32x4  bv1[2], bv2[2];
    unsigned rmask = 0;
    #pragma unroll
    for (int cc = 0; cc < 2; ++cc) {
        const int ct = 2 * wv + cc;
        bv1[cc] = *(const f32x4*)&b1[ct * 16 + q * 4];
        bv2[cc] = *(const f32x4*)&b2[ct * 16 + q * 4];
        f32x4 r4 = *(const f32x4*)&rru[ct * 16 + q * 4];
        #pragma unroll
        for (int reg = 0; reg < 4; ++reg)
            if (r4[reg] < 0.95f) rmask |= 1u << (cc * 4 + reg);
        #pragma unroll
        for (int ks = 0; ks < 5; ++ks) {
            wf1[cc][ks] = *(const bf16x8*)(w1t + (ct * 16 + m) * FDIM + ks * 32 + q * 8);
            wf2[cc][ks] = *(const bf16x8*)(w2t + (ct * 16 + m) * FDIM + ks * 32 + q * 8);
        }
    }
    bf16x8 wsf[4];
    #pragma unroll
    for (int ks2 = 0; ks2 < 4; ++ks2)
        #pragma unroll
        for (int j = 0; j < 8; ++j) {
            int h = ks2 * 32 + q * 8 + j;
            wsf[ks2][j] = (__bf16)((m < 10) ? Ws[h * 10 + m] : 0.0f);
        }
    const float bsv = (m < 10) ? bs[m] : 0.0f;

    const int nslab = B >> 4;
    auto stage = [&](int buf, int slab) {
        const int r0 = slab << 4;
        const float* x1p = x1 + (size_t)(r0 + m) * FDIM + q * 8;
        const float* x2p = x2 + (size_t)(r0 + m) * FDIM + q * 8;
        const float* nzp = noise + (size_t)(r0 + m) * HDIM + q * 4;
        #pragma unroll
        for (int j = 0; j < 7; ++j) {
            const int c = wv * 7 + j;                    // uniform per wave
            const float* g;
            if (c < 10)      g = x1p + (c >> 1) * 32 + (c & 1) * 4;
            else if (c < 20) g = x2p + ((c - 10) >> 1) * 32 + ((c - 10) & 1) * 4;
            else             g = nzp + (c - 20) * 16;
            GL2LDS(g, &stg[buf][c * 1024]);
        }
    };

    int it = blockIdx.x, cur = 0;
    stage(0, it);
    for (; it < nslab; it += gridDim.x) {
        asm volatile("s_waitcnt vmcnt(0)" ::: "memory");
        __syncthreads();                                  // buf[cur] staged; sbuf free
        if (it + (int)gridDim.x < nslab) stage(cur ^ 1, it + gridDim.x);

        f32x4 acc1[2] = { bv1[0], bv1[1] }, acc2[2] = { bv2[0], bv2[1] };
        #pragma unroll
        for (int ks = 0; ks < 5; ++ks) {
            f32x4 lo1 = *(const f32x4*)&stg[cur][(2 * ks) * 1024 + lane * 16];
            f32x4 hi1 = *(const f32x4*)&stg[cur][(2 * ks + 1) * 1024 + lane * 16];
            f32x4 lo2 = *(const f32x4*)&stg[cur][(10 + 2 * ks) * 1024 + lane * 16];
            f32x4 hi2 = *(const f32x4*)&stg[cur][(11 + 2 * ks) * 1024 + lane * 16];
            bf16x8 a1 = pack8(lo1, hi1), a2 = pack8(lo2, hi2);
            acc1[0] = __builtin_amdgcn_mfma_f32_16x16x32_bf16(wf1[0][ks], a1, acc1[0], 0, 0, 0);
            acc1[1] = __builtin_amdgcn_mfma_f32_16x16x32_bf16(wf1[1][ks], a1, acc1[1], 0, 0, 0);
            acc2[0] = __builtin_amdgcn_mfma_f32_16x16x32_bf16(wf2[0][ks], a2, acc2[0], 0, 0, 0);
            acc2[1] = __builtin_amdgcn_mfma_f32_16x16x32_bf16(wf2[1][ks], a2, acc2[1], 0, 0, 0);
        }
        #pragma unroll
        for (int cc = 0; cc < 2; ++cc) {
            f32x4 nz = *(const f32x4*)&stg[cur][(20 + 2 * wv + cc) * 1024 + lane * 16];
            bf16x4 pk;
            #pragma unroll
            for (int reg = 0; reg < 4; ++reg) {
                float v1 = acc1[cc][reg] + nz[reg] * noise_mul;
                v1 = ((rmask >> (cc * 4 + reg)) & 1u) ? v1 : 0.0f;
                pk[reg] = (__bf16)fminf(v1, acc2[cc][reg]);
            }
            *(bf16x4*)&sbuf[m * SROW + (2 * wv + cc) * 16 + q * 4] = pk;
        }
        __syncthreads();                                  // sbuf complete
        if (wv == 0) {
            f32x4 d = { bsv, bsv, bsv, bsv };
            #pragma unroll
            for (int ks2 = 0; ks2 < 4; ++ks2) {
                bf16x8 sf = *(const bf16x8*)&sbuf[m * SROW + ks2 * 32 + q * 8];
                d = __builtin_amdgcn_mfma_f32_16x16x32_bf16(sf, wsf[ks2], d, 0, 0, 0);
            }
            if (m < 10) {
                #pragma unroll
                for (int reg = 0; reg < 4; ++reg)
                    obuf[(q * 4 + reg) * 10 + m] = d[reg];
            }
            asm volatile("s_waitcnt lgkmcnt(0)" ::: "memory");
            if (lane < 40) {
                f32x4 o = *(const f32x4*)&obuf[lane * 4];
                *(f32x4*)(out + (size_t)it * 160 + lane * 4) = o;  // 640B dense per slab
            }
        }
        cur ^= 1;
    }
}

extern "C" void kernel_launch(void* const* d_in, const int* in_sizes, int n_in,
                              void* d_out, int out_size, void* d_ws, size_t ws_size,
                              hipStream_t stream) {
    const float* x1    = (const float*)d_in[0];
    const float* x2    = (const float*)d_in[1];
    const float* W1    = (const float*)d_in[2];
    const float* b1    = (const float*)d_in[3];
    const float* W2    = (const float*)d_in[4];
    const float* b2    = (const float*)d_in[5];
    const float* Ws    = (const float*)d_in[6];
    const float* bs    = (const float*)d_in[7];
    const float* noise = (const float*)d_in[8];
    const float* rru   = (const float*)d_in[9];
    float* out = (float*)d_out;
    const int B = in_sizes[0] / FDIM;

    unsigned int* mmx = (unsigned int*)d_ws;
    __bf16* w1t = (__bf16*)((char*)d_ws + 256);                 // 160*128*2 = 40960 B
    __bf16* w2t = (__bf16*)((char*)d_ws + 256 + 40960);

    hipLaunchKernelGGL(k0_prep, dim3(64), dim3(256), 0, stream, W1, W2, mmx, w1t, w2t);
    hipLaunchKernelGGL(k1_sens, dim3(1024), dim3(256), 0, stream, x1, b1, w1t, mmx, B);
    hipLaunchKernelGGL(k2_main, dim3(512), dim3(256), 0, stream,
                       x1, x2, b1, b2, Ws, bs, noise, rru, w1t, w2t, mmx, out, B);
}